// Round 6
// baseline (339.650 us; speedup 1.0000x reference)
//
#include <hip/hip_runtime.h>
#include <stdint.h>

typedef float f4 __attribute__((ext_vector_type(4)));

#define DF 128    // input feature dim
#define HID 64    // hidden dim
#define TN 64     // nodes per GEMM block
#define EPB 16384 // edges per pass-A block

// ---------- A1: per-block coarse histogram (LDS atomics only) ----------
__global__ __launch_bounds__(256) void kA1(const int* __restrict__ col,
                                           int* __restrict__ cnt,
                                           int E, int nbin) {
    __shared__ int hist[512];
    int b = blockIdx.x, t = threadIdx.x;
    for (int i = t; i < nbin; i += 256) hist[i] = 0;
    __syncthreads();
    int s = b * EPB, e = min(E, s + EPB);
    for (int i = s + t; i < e; i += 256) atomicAdd(&hist[col[i] >> 8], 1);
    __syncthreads();
    for (int i = t; i < nbin; i += 256) cnt[b * nbin + i] = hist[i];
}

// ---------- A2: cnt[block][bin] -> absolute slot bases; bbase = bucket bases ----------
__global__ __launch_bounds__(512) void kA2(int* __restrict__ cnt,
                                           int* __restrict__ bbase,
                                           int nbin, int nblk, int E) {
    __shared__ int lds[512];
    int t = threadIdx.x;
    int total = 0;
    if (t < nbin) {
        for (int b = 0; b < nblk; ++b) {
            int c = cnt[b * nbin + t];
            cnt[b * nbin + t] = total;
            total += c;
        }
    }
    lds[t] = (t < nbin) ? total : 0;
    __syncthreads();
    int val = lds[t];
    for (int d = 1; d < 512; d <<= 1) {
        int x = (t >= d) ? lds[t - d] : 0;
        __syncthreads();
        lds[t] += x;
        __syncthreads();
    }
    int base = lds[t] - val;   // exclusive scan over bucket totals
    if (t < nbin) {
        bbase[t] = base;
        for (int b = 0; b < nblk; ++b) cnt[b * nbin + t] += base;
    }
    if (t == 0) bbase[nbin] = E;
}

// ---------- A3: scatter edges into coarse buckets (LDS atomics only) ----------
__global__ __launch_bounds__(256) void kA3(const int* __restrict__ row,
                                           const int* __restrict__ col,
                                           const float* __restrict__ ew,
                                           const int* __restrict__ cnt,
                                           int2* __restrict__ tmp,
                                           int E, int nbin) {
    __shared__ int base[512];
    int b = blockIdx.x, t = threadIdx.x;
    for (int i = t; i < nbin; i += 256) base[i] = cnt[b * nbin + i];
    __syncthreads();
    int s = b * EPB, e = min(E, s + EPB);
    for (int i = s + t; i < e; i += 256) {
        int c = col[i];
        int bin = c >> 8;
        int slot = atomicAdd(&base[bin], 1);
        int2 pr;
        pr.x = row[i] | ((c & 255) << 24);   // src fits in 17 bits
        pr.y = __float_as_int(ew[i]);
        tmp[slot] = pr;
    }
}

// ---------- B: fine CSR within bucket + off + fused deg/rsqrt ----------
__global__ __launch_bounds__(256) void kB(const int2* __restrict__ tmp,
                                          const int* __restrict__ bbase,
                                          int2* __restrict__ edata,
                                          int* __restrict__ off,
                                          float* __restrict__ dinv,
                                          int N) {
    __shared__ int lds[256];
    __shared__ int basel[256];
    __shared__ int startl[256];
    int bin = blockIdx.x, t = threadIdx.x;
    int s = bbase[bin], e = bbase[bin + 1];

    lds[t] = 0;
    __syncthreads();
    for (int i = s + t; i < e; i += 256) {
        int lo = ((unsigned)tmp[i].x) >> 24;
        atomicAdd(&lds[lo], 1);
    }
    __syncthreads();
    int val = lds[t];
    __syncthreads();
    for (int d = 1; d < 256; d <<= 1) {
        int x = (t >= d) ? lds[t - d] : 0;
        __syncthreads();
        lds[t] += x;
        __syncthreads();
    }
    int myoff = s + lds[t] - val;   // exclusive within bucket, absolute
    int c = bin * 256 + t;
    if (c <= N) off[c] = myoff;
    startl[t] = myoff;
    basel[t]  = myoff;
    __syncthreads();
    for (int i = s + t; i < e; i += 256) {
        int2 pr = tmp[i];
        int lo = ((unsigned)pr.x) >> 24;
        int slot = atomicAdd(&basel[lo], 1);
        int2 o;
        o.x = pr.x & 0x00FFFFFF;
        o.y = pr.y;
        edata[slot] = o;
    }
    __syncthreads();
    if (c < N) {
        int b0 = startl[t], b1 = basel[t];
        float d = 1.0f;   // self-loop
        for (int i = b0; i < b1; ++i) d += __int_as_float(edata[i].y);
        dinv[c] = d > 0.f ? rsqrtf(d) : 0.f;
    }
}

// ---------- fold dinv[src] into edge weight ----------
__global__ __launch_bounds__(256) void k_snorm(int2* __restrict__ edata,
                                               const float* __restrict__ dinv, int E) {
    int i = blockIdx.x * 256 + threadIdx.x;
    if (i < E) {
        int2 pr = edata[i];
        pr.y = __float_as_int(__int_as_float(pr.y) * dinv[pr.x]);
        edata[i] = pr;
    }
}

// ---------- h = x @ W1  (N x 128 @ 128 x 64, fp32) ----------
__global__ __launch_bounds__(256) void k_gemm1(const float* __restrict__ x,
                                               const float* __restrict__ W1,
                                               float* __restrict__ h, int N) {
    __shared__ float xs[TN][DF];     // 32 KB
    __shared__ float ws[DF][HID];    // 32 KB
    int tid  = threadIdx.x;
    int node0 = blockIdx.x * TN;

    for (int f = tid; f < TN * (DF / 4); f += 256) {
        int n = f >> 5, k4 = f & 31;
        f4 v = (f4)(0.f);
        if (node0 + n < N) v = ((const f4*)x)[(size_t)(node0 + n) * (DF / 4) + k4];
        *((f4*)&xs[n][k4 * 4]) = v;
    }
    for (int f = tid; f < DF * HID / 4; f += 256) {
        ((f4*)ws)[f] = ((const f4*)W1)[f];
    }
    __syncthreads();

    int tx = tid & 15, ty = tid >> 4;
    f4 acc[4];
    acc[0] = acc[1] = acc[2] = acc[3] = (f4)(0.f);

    for (int k4 = 0; k4 < DF / 4; ++k4) {
        f4 xv[4];
#pragma unroll
        for (int i = 0; i < 4; ++i) xv[i] = *((const f4*)&xs[ty * 4 + i][k4 * 4]);
#pragma unroll
        for (int j = 0; j < 4; ++j) {
            f4 wv = *((const f4*)&ws[k4 * 4 + j][tx * 4]);
#pragma unroll
            for (int i = 0; i < 4; ++i) acc[i] += xv[i][j] * wv;
        }
    }

#pragma unroll
    for (int i = 0; i < 4; ++i) {
        int n = node0 + ty * 4 + i;
        if (n < N) ((f4*)h)[(size_t)n * (HID / 4) + tx] = acc[i];
    }
}

// ---------- fused layer-1 aggregate + relu + @W2 : one wave per node ----------
__global__ __launch_bounds__(256) void k_agg_h2(const int* __restrict__ off,
                                                const int2* __restrict__ edata,
                                                const float* __restrict__ dinv,
                                                const float* __restrict__ h,
                                                const float* __restrict__ b1,
                                                const float* __restrict__ W2,
                                                float* __restrict__ h2, int N) {
    int v = blockIdx.x * 4 + (threadIdx.x >> 6);
    if (v >= N) return;
    int l = threadIdx.x & 63;
    float di = dinv[v];
    float acc = di * h[(size_t)v * 64 + l];   // self-loop (outer di applied later)
    int i0 = off[v], e0 = off[v + 1];

    for (int base = i0; base < e0; base += 64) {
        int idx = base + l;
        int   src_l = 0;
        float w_l   = 0.f;
        if (idx < e0) {
            int2 pr = edata[idx];
            src_l = pr.x;
            w_l   = __int_as_float(pr.y);
        }
        int cnt = min(64, e0 - base);
        int j = 0;
        for (; j + 3 < cnt; j += 4) {
            int   s0 = __shfl(src_l, j),     s1 = __shfl(src_l, j + 1);
            int   s2 = __shfl(src_l, j + 2), s3 = __shfl(src_l, j + 3);
            float w0 = __shfl(w_l, j),       w1 = __shfl(w_l, j + 1);
            float w2 = __shfl(w_l, j + 2),   w3 = __shfl(w_l, j + 3);
            float h0 = h[(size_t)s0 * 64 + l];
            float h1 = h[(size_t)s1 * 64 + l];
            float hh2 = h[(size_t)s2 * 64 + l];
            float h3 = h[(size_t)s3 * 64 + l];
            acc += w0 * h0;
            acc += w1 * h1;
            acc += w2 * hh2;
            acc += w3 * h3;
        }
        for (; j < cnt; ++j) {
            int   s = __shfl(src_l, j);
            float w = __shfl(w_l, j);
            acc += w * h[(size_t)s * 64 + l];
        }
    }
    acc = di * acc;

    float s = fmaxf(acc + b1[l], 0.f) * W2[l];
    s += __shfl_down(s, 32);
    s += __shfl_down(s, 16);
    s += __shfl_down(s, 8);
    s += __shfl_down(s, 4);
    s += __shfl_down(s, 2);
    s += __shfl_down(s, 1);
    if (l == 0) h2[v] = s;
}

// ---------- layer-2 aggregation: 16 lanes per node ----------
__global__ __launch_bounds__(256) void k_out(const int* __restrict__ off,
                                             const int2* __restrict__ edata,
                                             const float* __restrict__ dinv,
                                             const float* __restrict__ h2,
                                             const float* __restrict__ b2,
                                             float* __restrict__ out, int N) {
    int t = blockIdx.x * 256 + threadIdx.x;
    int v = t >> 4;
    if (v >= N) return;
    int c = t & 15;
    int e0 = off[v + 1];
    float s = 0.f;
    for (int i = off[v] + c; i < e0; i += 16) {
        int2 pr = edata[i];
        s += __int_as_float(pr.y) * h2[pr.x];
    }
    s += __shfl_down(s, 8);
    s += __shfl_down(s, 4);
    s += __shfl_down(s, 2);
    s += __shfl_down(s, 1);
    if (c == 0) {
        float di = dinv[v];
        out[v] = b2[0] + di * (di * h2[v] + s);
    }
}

extern "C" void kernel_launch(void* const* d_in, const int* in_sizes, int n_in,
                              void* d_out, int out_size, void* d_ws, size_t ws_size,
                              hipStream_t stream) {
    const float* x  = (const float*)d_in[0];
    const int*   ei = (const int*)d_in[1];
    const float* ew = (const float*)d_in[2];
    const float* W1 = (const float*)d_in[3];
    const float* b1 = (const float*)d_in[4];
    const float* W2 = (const float*)d_in[5];
    const float* b2 = (const float*)d_in[6];
    float* out = (float*)d_out;

    const int N = in_sizes[0] / DF;       // 100000
    const int E = in_sizes[2];            // 1600000
    const int* row = ei;                  // sources
    const int* col = ei + E;              // targets

    const int nbin = (N + 255) / 256;     // 391 coarse buckets
    const int nblk = (E + EPB - 1) / EPB; // 98 pass-A blocks

    // ---- workspace layout, ~39.8 MB total (R4's 46.4 MB footprint proved safe;
    //      R5's 52.6 MB overflowed ws and corrupted harness memory) ----
    // tmp is dead after kB; h is first written by k_gemm1 (after kB) -> alias them.
    int*   w32   = (int*)d_ws;
    int2*  edata = (int2*)w32;                           // 2E ints   [0, 2E)
    int*   shreg = w32 + (size_t)2 * E;                  // shared region base (byte 12.8M, 16B aligned)
    int2*  tmp   = (int2*)shreg;                         // 2E ints   (build phase)
    float* h     = (float*)shreg;                        // N*64 ints (compute phase, aliases tmp)
    int*   p     = shreg + (size_t)N * HID;              // after the larger occupant (h)
    int*   cnt   = p;                                    // nblk*nbin
    p += ((nblk * nbin) + 3) & ~3;
    int*   bbase = p;                                    // nbin+1
    p += ((nbin + 1) + 3) & ~3;
    float* dinv  = (float*)p;  p += N;                   // N
    float* h2    = (float*)p;  p += N;                   // N
    int*   off   = p;                                    // N+1

    const int B = 256;
    int gE   = (E + B - 1) / B;
    int gG   = (N + TN - 1) / TN;
    int gAgg = (N + 3) / 4;
    int gN16 = (N * 16 + B - 1) / B;

    kA1<<<nblk, B, 0, stream>>>(col, cnt, E, nbin);
    kA2<<<1, 512, 0, stream>>>(cnt, bbase, nbin, nblk, E);
    kA3<<<nblk, B, 0, stream>>>(row, col, ew, cnt, tmp, E, nbin);
    kB<<<nbin, B, 0, stream>>>(tmp, bbase, edata, off, dinv, N);
    k_snorm<<<gE, B, 0, stream>>>(edata, dinv, E);
    k_gemm1<<<gG, B, 0, stream>>>(x, W1, h, N);
    k_agg_h2<<<gAgg, B, 0, stream>>>(off, edata, dinv, h, b1, W2, h2, N);
    k_out<<<gN16, B, 0, stream>>>(off, edata, dinv, h2, b2, out, N);
}

// Round 7
// 303.248 us; speedup vs baseline: 1.1200x; 1.1200x over previous
//
#include <hip/hip_runtime.h>
#include <stdint.h>

typedef float f4 __attribute__((ext_vector_type(4)));
typedef _Float16 h4 __attribute__((ext_vector_type(4)));

#define DF 128    // input feature dim
#define HID 64    // hidden dim
#define TN 64     // nodes per GEMM block
#define EPB 16384 // edges per pass-A block

// ---------- zero the per-bin totals ----------
__global__ __launch_bounds__(256) void kZ(int* __restrict__ gtot, int nbin) {
    int i = blockIdx.x * 256 + threadIdx.x;
    if (i < nbin) gtot[i] = 0;
}

// ---------- coarse histogram: per-block LDS hist, one global atomic per bin ----------
__global__ __launch_bounds__(256) void kH(const int* __restrict__ col,
                                          int* __restrict__ gtot, int E, int nbin) {
    __shared__ int hist[512];
    int b = blockIdx.x, t = threadIdx.x;
    for (int i = t; i < nbin; i += 256) hist[i] = 0;
    __syncthreads();
    int s = b * EPB, e = min(E, s + EPB);
    for (int i = s + t; i < e; i += 256) atomicAdd(&hist[col[i] >> 8], 1);
    __syncthreads();
    for (int i = t; i < nbin; i += 256) {
        int h = hist[i];
        if (h) atomicAdd(&gtot[i], h);
    }
}

// ---------- scan bucket totals -> bbase; init cur ----------
__global__ __launch_bounds__(512) void kScan(const int* __restrict__ gtot,
                                             int* __restrict__ bbase,
                                             int* __restrict__ cur, int nbin, int E) {
    __shared__ int lds[512];
    int t = threadIdx.x;
    int v = (t < nbin) ? gtot[t] : 0;
    lds[t] = v;
    __syncthreads();
    for (int d = 1; d < 512; d <<= 1) {
        int x = (t >= d) ? lds[t - d] : 0;
        __syncthreads();
        lds[t] += x;
        __syncthreads();
    }
    int base = lds[t] - v;   // exclusive
    if (t < nbin) { bbase[t] = base; cur[t] = base; }
    if (t == 0) bbase[nbin] = E;
}

// ---------- scatter into coarse buckets via chunk reservation ----------
__global__ __launch_bounds__(256) void kA3(const int* __restrict__ row,
                                           const int* __restrict__ col,
                                           const float* __restrict__ ew,
                                           int* __restrict__ cur,
                                           int2* __restrict__ tmp,
                                           int E, int nbin) {
    __shared__ int hist[512];
    __shared__ int lbase[512];
    int b = blockIdx.x, t = threadIdx.x;
    for (int i = t; i < nbin; i += 256) hist[i] = 0;
    __syncthreads();
    int s = b * EPB, e = min(E, s + EPB);
    for (int i = s + t; i < e; i += 256) atomicAdd(&hist[col[i] >> 8], 1);
    __syncthreads();
    for (int i = t; i < nbin; i += 256) {
        int h = hist[i];
        lbase[i] = h ? atomicAdd(&cur[i], h) : 0;   // reserve span for this block
        hist[i] = 0;                                 // reuse as rank counter
    }
    __syncthreads();
    for (int i = s + t; i < e; i += 256) {
        int c = col[i];
        int bin = c >> 8;
        int slot = lbase[bin] + atomicAdd(&hist[bin], 1);
        int2 pr;
        pr.x = row[i] | ((c & 255) << 24);   // src fits in 17 bits
        pr.y = __float_as_int(ew[i]);
        tmp[slot] = pr;
    }
}

// ---------- B: fine CSR within bucket + off + fused deg/rsqrt ----------
__global__ __launch_bounds__(256) void kB(const int2* __restrict__ tmp,
                                          const int* __restrict__ bbase,
                                          int2* __restrict__ edata,
                                          int* __restrict__ off,
                                          float* __restrict__ dinv,
                                          int N) {
    __shared__ int lds[256];
    __shared__ int basel[256];
    __shared__ int startl[256];
    int bin = blockIdx.x, t = threadIdx.x;
    int s = bbase[bin], e = bbase[bin + 1];

    lds[t] = 0;
    __syncthreads();
    for (int i = s + t; i < e; i += 256) {
        int lo = ((unsigned)tmp[i].x) >> 24;
        atomicAdd(&lds[lo], 1);
    }
    __syncthreads();
    int val = lds[t];
    __syncthreads();
    for (int d = 1; d < 256; d <<= 1) {
        int x = (t >= d) ? lds[t - d] : 0;
        __syncthreads();
        lds[t] += x;
        __syncthreads();
    }
    int myoff = s + lds[t] - val;   // exclusive within bucket, absolute
    int c = bin * 256 + t;
    if (c <= N) off[c] = myoff;
    startl[t] = myoff;
    basel[t]  = myoff;
    __syncthreads();
    for (int i = s + t; i < e; i += 256) {
        int2 pr = tmp[i];
        int lo = ((unsigned)pr.x) >> 24;
        int slot = atomicAdd(&basel[lo], 1);
        int2 o;
        o.x = pr.x & 0x00FFFFFF;
        o.y = pr.y;
        edata[slot] = o;
    }
    __syncthreads();
    if (c < N) {
        int b0 = startl[t], b1 = basel[t];
        float d = 1.0f;   // self-loop
        for (int i = b0; i < b1; ++i) d += __int_as_float(edata[i].y);
        dinv[c] = d > 0.f ? rsqrtf(d) : 0.f;
    }
}

// ---------- fold dinv[src] into edge weight ----------
__global__ __launch_bounds__(256) void k_snorm(int2* __restrict__ edata,
                                               const float* __restrict__ dinv, int E) {
    int i = blockIdx.x * 256 + threadIdx.x;
    if (i < E) {
        int2 pr = edata[i];
        pr.y = __float_as_int(__int_as_float(pr.y) * dinv[pr.x]);
        edata[i] = pr;
    }
}

// ---------- h = x @ W1  (N x 128 @ 128 x 64, fp32 compute, fp16 store) ----------
__global__ __launch_bounds__(256) void k_gemm1(const float* __restrict__ x,
                                               const float* __restrict__ W1,
                                               _Float16* __restrict__ h, int N) {
    __shared__ float xs[TN][DF];     // 32 KB
    __shared__ float ws[DF][HID];    // 32 KB
    int tid  = threadIdx.x;
    int node0 = blockIdx.x * TN;

    for (int f = tid; f < TN * (DF / 4); f += 256) {
        int n = f >> 5, k4 = f & 31;
        f4 v = (f4)(0.f);
        if (node0 + n < N) v = ((const f4*)x)[(size_t)(node0 + n) * (DF / 4) + k4];
        *((f4*)&xs[n][k4 * 4]) = v;
    }
    for (int f = tid; f < DF * HID / 4; f += 256) {
        ((f4*)ws)[f] = ((const f4*)W1)[f];
    }
    __syncthreads();

    int tx = tid & 15, ty = tid >> 4;
    f4 acc[4];
    acc[0] = acc[1] = acc[2] = acc[3] = (f4)(0.f);

    for (int k4 = 0; k4 < DF / 4; ++k4) {
        f4 xv[4];
#pragma unroll
        for (int i = 0; i < 4; ++i) xv[i] = *((const f4*)&xs[ty * 4 + i][k4 * 4]);
#pragma unroll
        for (int j = 0; j < 4; ++j) {
            f4 wv = *((const f4*)&ws[k4 * 4 + j][tx * 4]);
#pragma unroll
            for (int i = 0; i < 4; ++i) acc[i] += xv[i][j] * wv;
        }
    }

#pragma unroll
    for (int i = 0; i < 4; ++i) {
        int n = node0 + ty * 4 + i;
        if (n < N) {
            h4 o;
            o.x = (_Float16)acc[i].x;
            o.y = (_Float16)acc[i].y;
            o.z = (_Float16)acc[i].z;
            o.w = (_Float16)acc[i].w;
            ((h4*)h)[(size_t)n * 16 + tx] = o;
        }
    }
}

// ---------- fused layer-1 aggregate + relu + @W2 : one wave per node ----------
__global__ __launch_bounds__(256) void k_agg_h2(const int* __restrict__ off,
                                                const int2* __restrict__ edata,
                                                const float* __restrict__ dinv,
                                                const _Float16* __restrict__ h,
                                                const float* __restrict__ b1,
                                                const float* __restrict__ W2,
                                                float* __restrict__ h2, int N) {
    int v = blockIdx.x * 4 + (threadIdx.x >> 6);
    if (v >= N) return;
    int l = threadIdx.x & 63;
    float di = dinv[v];
    float acc = di * (float)h[(size_t)v * 64 + l];   // self-loop (outer di later)
    int i0 = off[v], e0 = off[v + 1];

    for (int base = i0; base < e0; base += 64) {
        int idx = base + l;
        int   src_l = 0;
        float w_l   = 0.f;
        if (idx < e0) {
            int2 pr = edata[idx];
            src_l = pr.x;
            w_l   = __int_as_float(pr.y);
        }
        int cnt = min(64, e0 - base);
        int j = 0;
        for (; j + 3 < cnt; j += 4) {
            int   s0 = __shfl(src_l, j),     s1 = __shfl(src_l, j + 1);
            int   s2 = __shfl(src_l, j + 2), s3 = __shfl(src_l, j + 3);
            float w0 = __shfl(w_l, j),       w1 = __shfl(w_l, j + 1);
            float w2 = __shfl(w_l, j + 2),   w3 = __shfl(w_l, j + 3);
            float h0 = (float)h[(size_t)s0 * 64 + l];
            float h1 = (float)h[(size_t)s1 * 64 + l];
            float hh2 = (float)h[(size_t)s2 * 64 + l];
            float h3 = (float)h[(size_t)s3 * 64 + l];
            acc += w0 * h0;
            acc += w1 * h1;
            acc += w2 * hh2;
            acc += w3 * h3;
        }
        for (; j < cnt; ++j) {
            int   s = __shfl(src_l, j);
            float w = __shfl(w_l, j);
            acc += w * (float)h[(size_t)s * 64 + l];
        }
    }
    acc = di * acc;

    float s = fmaxf(acc + b1[l], 0.f) * W2[l];
    s += __shfl_down(s, 32);
    s += __shfl_down(s, 16);
    s += __shfl_down(s, 8);
    s += __shfl_down(s, 4);
    s += __shfl_down(s, 2);
    s += __shfl_down(s, 1);
    if (l == 0) h2[v] = s;
}

// ---------- layer-2 aggregation: 16 lanes per node ----------
__global__ __launch_bounds__(256) void k_out(const int* __restrict__ off,
                                             const int2* __restrict__ edata,
                                             const float* __restrict__ dinv,
                                             const float* __restrict__ h2,
                                             const float* __restrict__ b2,
                                             float* __restrict__ out, int N) {
    int t = blockIdx.x * 256 + threadIdx.x;
    int v = t >> 4;
    if (v >= N) return;
    int c = t & 15;
    int e0 = off[v + 1];
    float s = 0.f;
    for (int i = off[v] + c; i < e0; i += 16) {
        int2 pr = edata[i];
        s += __int_as_float(pr.y) * h2[pr.x];
    }
    s += __shfl_down(s, 8);
    s += __shfl_down(s, 4);
    s += __shfl_down(s, 2);
    s += __shfl_down(s, 1);
    if (c == 0) {
        float di = dinv[v];
        out[v] = b2[0] + di * (di * h2[v] + s);
    }
}

extern "C" void kernel_launch(void* const* d_in, const int* in_sizes, int n_in,
                              void* d_out, int out_size, void* d_ws, size_t ws_size,
                              hipStream_t stream) {
    const float* x  = (const float*)d_in[0];
    const int*   ei = (const int*)d_in[1];
    const float* ew = (const float*)d_in[2];
    const float* W1 = (const float*)d_in[3];
    const float* b1 = (const float*)d_in[4];
    const float* W2 = (const float*)d_in[5];
    const float* b2 = (const float*)d_in[6];
    float* out = (float*)d_out;

    const int N = in_sizes[0] / DF;       // 100000
    const int E = in_sizes[2];            // 1600000
    const int* row = ei;                  // sources
    const int* col = ei + E;              // targets

    const int nbin = (N + 255) / 256;     // 391 coarse buckets
    const int nblk = (E + EPB - 1) / EPB; // 98 pass-A blocks

    // ---- workspace layout, ~27 MB (proven-safe budget ~40 MB) ----
    // tmp (build, 12.8 MB) aliases h (fp16 compute, 12.8 MB): tmp dead after kB,
    // h first written by k_gemm1 which runs after kB on the same stream.
    int*      w32   = (int*)d_ws;
    int2*     edata = (int2*)w32;                         // 2E ints = 12.8 MB
    int*      shreg = w32 + (size_t)2 * E;                // shared 12.8 MB region
    int2*     tmp   = (int2*)shreg;                       // build phase
    _Float16* h     = (_Float16*)shreg;                   // compute phase (N*64 fp16)
    int*      p     = shreg + (size_t)2 * E;              // end of shared region
    int*      gtot  = p;  p += ((nbin) + 3) & ~3;         // nbin
    int*      bbase = p;  p += ((nbin + 1) + 3) & ~3;     // nbin+1
    int*      cur   = p;  p += ((nbin) + 3) & ~3;         // nbin
    float*    dinv  = (float*)p;  p += N;                 // N
    float*    h2    = (float*)p;  p += N;                 // N
    int*      off   = p;                                  // N+1

    const int B = 256;
    int gE   = (E + B - 1) / B;
    int gG   = (N + TN - 1) / TN;
    int gAgg = (N + 3) / 4;
    int gN16 = (N * 16 + B - 1) / B;

    kZ<<<(nbin + 255) / 256, B, 0, stream>>>(gtot, nbin);
    kH<<<nblk, B, 0, stream>>>(col, gtot, E, nbin);
    kScan<<<1, 512, 0, stream>>>(gtot, bbase, cur, nbin, E);
    kA3<<<nblk, B, 0, stream>>>(row, col, ew, cur, tmp, E, nbin);
    kB<<<nbin, B, 0, stream>>>(tmp, bbase, edata, off, dinv, N);
    k_snorm<<<gE, B, 0, stream>>>(edata, dinv, E);
    k_gemm1<<<gG, B, 0, stream>>>(x, W1, h, N);
    k_agg_h2<<<gAgg, B, 0, stream>>>(off, edata, dinv, h, b1, W2, h2, N);
    k_out<<<gN16, B, 0, stream>>>(off, edata, dinv, h2, b2, out, N);
}